// Round 9
// baseline (83.336 us; speedup 1.0000x reference)
//
#include <hip/hip_runtime.h>

#define TWO_LOG2E 2.8853900817779268f

__device__ __forceinline__ float frcp(float x) {
#if __has_builtin(__builtin_amdgcn_rcpf)
  return __builtin_amdgcn_rcpf(x);
#else
  return 1.0f / x;
#endif
}
__device__ __forceinline__ float fexp2(float x) {
#if __has_builtin(__builtin_amdgcn_exp2f)
  return __builtin_amdgcn_exp2f(x);
#else
  return exp2f(x);
#endif
}
__device__ __forceinline__ unsigned short f2bf(float f) {  // RNE f32->bf16
  unsigned int u = __float_as_uint(f);
  u += 0x7fffu + ((u >> 16) & 1u);
  return (unsigned short)(u >> 16);
}
__device__ __forceinline__ unsigned int pack2bf(float lo, float hi) {
  return (unsigned int)f2bf(lo) | ((unsigned int)f2bf(hi) << 16);
}

using short8 = __attribute__((ext_vector_type(8))) short;
using f32x4v = __attribute__((ext_vector_type(4))) float;
using f32x16s = __attribute__((ext_vector_type(16))) float;

// sum_{i=0..3} v_i/x_i with ONE rcp:  num/denom form.
__device__ __forceinline__ void cell4(float a0, float a1, float a2, float a3,
                                      float b0, float b1, float b2, float b3,
                                      float v0, float v1, float v2, float v3,
                                      float& s) {
  float x0 = fmaf(a0, b0, 1.f), x1 = fmaf(a1, b1, 1.f);
  float x2 = fmaf(a2, b2, 1.f), x3 = fmaf(a3, b3, 1.f);
  float p01 = x0 * x1, p23 = x2 * x3;
  float n01 = fmaf(v0, x1, v1 * x0);
  float n23 = fmaf(v2, x3, v3 * x2);
  float num = fmaf(n01, p23, n23 * p01);
  s = fmaf(num, frcp(p01 * p23), s);
}

// ---------------------------------------------------------------------------
// K1: Aexp[m][128] = exp(2*query@w1^T) (f32),
//     BexpT[h][4096] = exp(2*key@w2^T) TRANSPOSED (bf16)
// via bf16 MFMA 16x16x32. M=4096, N=128 (full), K=512. BM=32, BN=128, BK=64.
// grid (128, 2): y = 0 -> query/w1/Aout, 1 -> key/w2/BoutT. block 256.
// ---------------------------------------------------------------------------
__global__ __launch_bounds__(256) void k_proj_mfma(
    const float* __restrict__ query, const float* __restrict__ key,
    const float* __restrict__ w1, const float* __restrict__ w2,
    float* __restrict__ Aout, unsigned short* __restrict__ BoutT) {
  const float* in = blockIdx.y ? key : query;
  const float* wm = blockIdx.y ? w2  : w1;

  __shared__ __align__(16) char Abuf[32 * 128];   // [m][k] bf16, swizzled, 4KB
  __shared__ __align__(16) char Bbuf[128 * 128];  // [n][k] bf16, swizzled, 16KB

  const int t = threadIdx.x;
  const int m0g = blockIdx.x * 32;
  const int w = t >> 6, l = t & 63;
  const int wr = w >> 1, wc = w & 1;  // m-half(16) / n-half(64)

  f32x4v acc[4];
  acc[0] = 0; acc[1] = 0; acc[2] = 0; acc[3] = 0;

  const int srow = t >> 3, sg = t & 7;  // staging: row, granule

  for (int k0 = 0; k0 < 512; k0 += 64) {
    if (k0) __syncthreads();
    {  // stage A tile 32m x 64k: 1 granule (8 floats -> 8 bf16) per thread
      const float* src = &in[(m0g + srow) * 512 + k0 + sg * 8];
      float4 f0 = *(const float4*)src;
      float4 f1 = *(const float4*)(src + 4);
      uint4 p = make_uint4(pack2bf(f0.x, f0.y), pack2bf(f0.z, f0.w),
                           pack2bf(f1.x, f1.y), pack2bf(f1.z, f1.w));
      *(uint4*)(Abuf + srow * 128 + ((sg ^ (srow & 7)) << 4)) = p;
    }
#pragma unroll
    for (int i = 0; i < 4; ++i) {  // stage w tile 128n x 64k: 4 granules/thread
      int tt = t + i * 256;
      int row = tt >> 3, g = tt & 7;
      const float* src = &wm[row * 512 + k0 + g * 8];
      float4 f0 = *(const float4*)src;
      float4 f1 = *(const float4*)(src + 4);
      uint4 p = make_uint4(pack2bf(f0.x, f0.y), pack2bf(f0.z, f0.w),
                           pack2bf(f1.x, f1.y), pack2bf(f1.z, f1.w));
      *(uint4*)(Bbuf + row * 128 + ((g ^ (row & 7)) << 4)) = p;
    }
    __syncthreads();
#pragma unroll
    for (int ks = 0; ks < 2; ++ks) {
      const int gb = ks * 4 + (l >> 4);
      int ra = wr * 16 + (l & 15);
      short8 af = *(const short8*)(Abuf + ra * 128 + ((gb ^ (ra & 7)) << 4));
#pragma unroll
      for (int ni = 0; ni < 4; ++ni) {
        int rb = wc * 64 + ni * 16 + (l & 15);
        short8 bf_ = *(const short8*)(Bbuf + rb * 128 + ((gb ^ (rb & 7)) << 4));
        acc[ni] = __builtin_amdgcn_mfma_f32_16x16x32_bf16(af, bf_, acc[ni], 0, 0, 0);
      }
    }
  }
#pragma unroll
  for (int ni = 0; ni < 4; ++ni) {
    int col = wc * 64 + ni * 16 + (l & 15);  // h
#pragma unroll
    for (int j = 0; j < 4; ++j) {
      int row = m0g + wr * 16 + (l >> 4) * 4 + j;  // m
      float val = fexp2(acc[ni][j] * TWO_LOG2E);
      if (blockIdx.y == 0)
        Aout[row * 128 + col] = val;
      else
        BoutT[col * 4096 + row] = f2bf(val);  // transposed store
    }
  }
}

// ---------------------------------------------------------------------------
// k_valT: valT[b][n][k] = bf16(value[b][k][n]).  64x64 tiles, grid (8,8,8).
// ---------------------------------------------------------------------------
__global__ __launch_bounds__(256) void k_valT(
    const float* __restrict__ value, unsigned short* __restrict__ valT) {
  __shared__ unsigned short ts[64][66];
  const int t = threadIdx.x;
  const int b = blockIdx.z, k0 = blockIdx.y * 64, n0 = blockIdx.x * 64;
  {
    int kr = t >> 4, n4 = (t & 15) * 4;
#pragma unroll
    for (int i = 0; i < 4; ++i) {
      float4 f = *(const float4*)&value[((b * 512) + k0 + kr + 16 * i) * 512 + n0 + n4];
      *(ushort4*)&ts[kr + 16 * i][n4] =
          make_ushort4(f2bf(f.x), f2bf(f.y), f2bf(f.z), f2bf(f.w));
    }
  }
  __syncthreads();
  {
    int nw = t >> 4, k4 = (t & 15) * 4;
#pragma unroll
    for (int i = 0; i < 4; ++i) {
      int n = nw + 16 * i;
      ushort4 o = make_ushort4(ts[k4 + 0][n], ts[k4 + 1][n], ts[k4 + 2][n], ts[k4 + 3][n]);
      *(ushort4*)&valT[((b * 512) + n0 + n) * 512 + k0 + k4] = o;
    }
  }
}

// ---------------------------------------------------------------------------
// K2: S[q,k] = sum_h v[h]/(A[q,h]*B[k,h]+1);  attn = softmax_k(-2S).
// NO LDS, NO barriers in the hot loop. B read from BexpT[h][k] (h-major):
// lane l owns k = wav*128 + 2l + {0,1}; per h one coalesced dword load
// (2 bf16 k-neighbors). A,v SGPR-broadcast via s_load_dwordx16 (16-h chunks,
// 8 lgkm waits total). 2 q-rows/block. grid (256,8) = 8 blocks/CU.
// ---------------------------------------------------------------------------
__global__ __launch_bounds__(256, 8) void k_score_softmax(
    const float* __restrict__ Aexp, const unsigned short* __restrict__ BexpT,
    const float* __restrict__ vw, float* __restrict__ attn) {
  __shared__ float red[4][2];

  const int tid = threadIdx.x;
  const int b = blockIdx.y;
  const int qbase = blockIdx.x * 2;
  const int wav = tid >> 6;   // k-quarter
  const int lane = tid & 63;

  // per-lane B base: element (h=0, k = b*512 + wav*128 + 2*lane)
  const unsigned short* const bbase = BexpT + b * 512 + wav * 128 + lane * 2;

  // wave-uniform scalar base pointers for the 2 A rows and v
  const float* const pa0 =
      Aexp + __builtin_amdgcn_readfirstlane((b * 512 + qbase) * 128);
  const float* const pa1 = pa0 + 128;
  const float* const pv = vw;

  float S00 = 0.f, S01 = 0.f, S10 = 0.f, S11 = 0.f;  // [q][kk]

#pragma unroll
  for (int hc = 0; hc < 8; ++hc) {
    // B loads first (vmcnt pipe) so they fly during the SMEM wait.
    unsigned bq[16];
#pragma unroll
    for (int j = 0; j < 16; ++j)
      bq[j] = *(const unsigned*)(bbase + (hc * 16 + j) * 4096);

    f32x16s sa0, sa1, sv;
    unsigned soff = (unsigned)(hc * 64);
    asm volatile(
        "s_load_dwordx16 %0, %3, %6\n\t"
        "s_load_dwordx16 %1, %4, %6\n\t"
        "s_load_dwordx16 %2, %5, %6\n\t"
        "s_waitcnt lgkmcnt(0)"
        : "=&s"(sa0), "=&s"(sa1), "=&s"(sv)
        : "s"(pa0), "s"(pa1), "s"(pv), "s"(soff));

#pragma unroll
    for (int g = 0; g < 4; ++g) {
      float bk0[4], bk1[4];
#pragma unroll
      for (int i = 0; i < 4; ++i) {
        unsigned u = bq[g * 4 + i];
        bk0[i] = __uint_as_float(u << 16);         // k even
        bk1[i] = __uint_as_float(u & 0xffff0000u); // k odd
      }
      const int h = g * 4;
      cell4(sa0[h], sa0[h + 1], sa0[h + 2], sa0[h + 3],
            bk0[0], bk0[1], bk0[2], bk0[3],
            sv[h], sv[h + 1], sv[h + 2], sv[h + 3], S00);
      cell4(sa0[h], sa0[h + 1], sa0[h + 2], sa0[h + 3],
            bk1[0], bk1[1], bk1[2], bk1[3],
            sv[h], sv[h + 1], sv[h + 2], sv[h + 3], S01);
      cell4(sa1[h], sa1[h + 1], sa1[h + 2], sa1[h + 3],
            bk0[0], bk0[1], bk0[2], bk0[3],
            sv[h], sv[h + 1], sv[h + 2], sv[h + 3], S10);
      cell4(sa1[h], sa1[h + 1], sa1[h + 2], sa1[h + 3],
            bk1[0], bk1[1], bk1[2], bk1[3],
            sv[h], sv[h + 1], sv[h + 2], sv[h + 3], S11);
    }
  }

  // softmax over k of (-2S): max(score) <-> min(S). k spans lanes+waves.
  float mn0 = fminf(S00, S01);
  float mn1 = fminf(S10, S11);
#pragma unroll
  for (int off = 32; off > 0; off >>= 1) {
    mn0 = fminf(mn0, __shfl_xor(mn0, off));
    mn1 = fminf(mn1, __shfl_xor(mn1, off));
  }
  if (lane == 0) { red[wav][0] = mn0; red[wav][1] = mn1; }
  __syncthreads();
  mn0 = fminf(fminf(red[0][0], red[1][0]), fminf(red[2][0], red[3][0]));
  mn1 = fminf(fminf(red[0][1], red[1][1]), fminf(red[2][1], red[3][1]));
  __syncthreads();  // before red reuse

  float P00 = fexp2((mn0 - S00) * TWO_LOG2E);
  float P01 = fexp2((mn0 - S01) * TWO_LOG2E);
  float P10 = fexp2((mn1 - S10) * TWO_LOG2E);
  float P11 = fexp2((mn1 - S11) * TWO_LOG2E);
  float sum0 = P00 + P01, sum1 = P10 + P11;
#pragma unroll
  for (int off = 32; off > 0; off >>= 1) {
    sum0 += __shfl_xor(sum0, off);
    sum1 += __shfl_xor(sum1, off);
  }
  if (lane == 0) { red[wav][0] = sum0; red[wav][1] = sum1; }
  __syncthreads();
  float r0 = frcp(red[0][0] + red[1][0] + red[2][0] + red[3][0]);
  float r1 = frcp(red[0][1] + red[1][1] + red[2][1] + red[3][1]);

  const int row0 = (b * 512 + qbase) * 512;
  const int k0 = wav * 128 + lane * 2;
  *(float2*)&attn[row0 + k0] = make_float2(P00 * r0, P01 * r0);
  *(float2*)&attn[row0 + 512 + k0] = make_float2(P10 * r1, P11 * r1);
}

// ---------------------------------------------------------------------------
// K3: context[b] = attn[b] @ value[b] via bf16 MFMA 16x16x32.
// Tile 64x64, BK=64, 4 waves (2x2), wave tile 32x32 (2x2 frags).
// grid (8,8,8), block 256.
// ---------------------------------------------------------------------------
__global__ __launch_bounds__(256) void k_context_mfma(
    const float* __restrict__ attn, const unsigned short* __restrict__ valT,
    float* __restrict__ ctx) {
  __shared__ __align__(16) char At[64 * 128];  // [m][k] bf16 swizzled, 8KB
  __shared__ __align__(16) char Bt[64 * 128];  // [n][k] bf16 swizzled, 8KB

  const int t = threadIdx.x;
  const int b = blockIdx.z;
  const int m0 = blockIdx.y * 64, n0 = blockIdx.x * 64;
  const int w = t >> 6, l = t & 63;
  const int wr = w >> 1, wc = w & 1;

  f32x4v acc[2][2];
  acc[0][0] = 0; acc[0][1] = 0; acc[1][0] = 0; acc[1][1] = 0;

  const int sr = t >> 2;
  const int sg = (t & 3);
  const int sswz = sr & 7;

  for (int k0 = 0; k0 < 512; k0 += 64) {
    if (k0) __syncthreads();
    {  // stage A: 16 f32 -> 16 bf16 per thread
      const float* src = &attn[(b * 512 + m0 + sr) * 512 + k0 + sg * 16];
      char* dst = At + sr * 128;
#pragma unroll
      for (int h = 0; h < 2; ++h) {
        float4 f0 = *(const float4*)(src + h * 8);
        float4 f1 = *(const float4*)(src + h * 8 + 4);
        uint4 p = make_uint4(pack2bf(f0.x, f0.y), pack2bf(f0.z, f0.w),
                             pack2bf(f1.x, f1.y), pack2bf(f1.z, f1.w));
        int g = sg * 2 + h;
        *(uint4*)(dst + ((g ^ sswz) << 4)) = p;
      }
      // stage B^T: 32 bf16 per thread (already bf16)
      const unsigned short* srcb = &valT[(b * 512 + n0 + sr) * 512 + k0];
      char* dstb = Bt + sr * 128;
#pragma unroll
      for (int h = 0; h < 2; ++h) {
        int g = sg + h * 4;
        uint4 vb = *(const uint4*)(srcb + g * 8);
        *(uint4*)(dstb + ((g ^ sswz) << 4)) = vb;
      }
    }
    __syncthreads();
#pragma unroll
    for (int ks = 0; ks < 2; ++ks) {
      const int gb = ks * 4 + (l >> 4);
      short8 af[2], bf_[2];
#pragma unroll
      for (int mi = 0; mi < 2; ++mi) {
        int ra = wr * 32 + mi * 16 + (l & 15);
        af[mi] = *(const short8*)(At + ra * 128 + ((gb ^ (ra & 7)) << 4));
      }
#pragma unroll
      for (int ni = 0; ni < 2; ++ni) {
        int rb = wc * 32 + ni * 16 + (l & 15);
        bf_[ni] = *(const short8*)(Bt + rb * 128 + ((gb ^ (rb & 7)) << 4));
      }
#pragma unroll
      for (int mi = 0; mi < 2; ++mi)
#pragma unroll
        for (int ni = 0; ni < 2; ++ni)
          acc[mi][ni] = __builtin_amdgcn_mfma_f32_16x16x32_bf16(
              af[mi], bf_[ni], acc[mi][ni], 0, 0, 0);
    }
  }
  __syncthreads();
#pragma unroll
  for (int mi = 0; mi < 2; ++mi)
#pragma unroll
    for (int ni = 0; ni < 2; ++ni) {
      int col = n0 + wc * 32 + ni * 16 + (l & 15);
#pragma unroll
      for (int j = 0; j < 4; ++j) {
        int row = m0 + wr * 32 + mi * 16 + (l >> 4) * 4 + j;
        ctx[(b * 512 + row) * 512 + col] = acc[mi][ni][j];
      }
    }
}

extern "C" void kernel_launch(void* const* d_in, const int* in_sizes, int n_in,
                              void* d_out, int out_size, void* d_ws, size_t ws_size,
                              hipStream_t stream) {
  const float* query = (const float*)d_in[0];
  const float* key   = (const float*)d_in[1];
  const float* value = (const float*)d_in[2];
  const float* w1    = (const float*)d_in[3];
  const float* w2    = (const float*)d_in[4];
  const float* v     = (const float*)d_in[5];

  float* attn = (float*)d_out;
  float* ctx  = attn + 8 * 512 * 512;

  float* Aexp = (float*)d_ws;                                    // 4096*128 f32
  unsigned short* BexpT = (unsigned short*)(Aexp + 4096 * 128);  // 128*4096 bf16
  unsigned short* valT = BexpT + 128 * 4096;                     // 8*512*512 bf16

  k_proj_mfma<<<dim3(128, 2), 256, 0, stream>>>(query, key, w1, w2, Aexp, BexpT);
  k_valT<<<dim3(8, 8, 8), 256, 0, stream>>>(value, valT);
  k_score_softmax<<<dim3(256, 8), 256, 0, stream>>>(Aexp, BexpT, v, attn);
  k_context_mfma<<<dim3(8, 8, 8), 256, 0, stream>>>(attn, valT, ctx);
}

// Round 10
// 66.646 us; speedup vs baseline: 1.2504x; 1.2504x over previous
//
#include <hip/hip_runtime.h>

#define TWO_LOG2E 2.8853900817779268f

__device__ __forceinline__ float frcp(float x) {
#if __has_builtin(__builtin_amdgcn_rcpf)
  return __builtin_amdgcn_rcpf(x);
#else
  return 1.0f / x;
#endif
}
__device__ __forceinline__ float fexp2(float x) {
#if __has_builtin(__builtin_amdgcn_exp2f)
  return __builtin_amdgcn_exp2f(x);
#else
  return exp2f(x);
#endif
}
__device__ __forceinline__ unsigned short f2bf(float f) {  // RNE f32->bf16
  unsigned int u = __float_as_uint(f);
  u += 0x7fffu + ((u >> 16) & 1u);
  return (unsigned short)(u >> 16);
}
__device__ __forceinline__ unsigned int pack2bf(float lo, float hi) {
  return (unsigned int)f2bf(lo) | ((unsigned int)f2bf(hi) << 16);
}

using short8 = __attribute__((ext_vector_type(8))) short;
using f32x4v = __attribute__((ext_vector_type(4))) float;
using f32x16s = __attribute__((ext_vector_type(16))) float;
using f32x2 = __attribute__((ext_vector_type(2))) float;

__device__ __forceinline__ f32x2 pkfma(f32x2 a, f32x2 b, f32x2 c) {
  return __builtin_elementwise_fma(a, b, c);
}
__device__ __forceinline__ f32x2 splat2(float x) {
  f32x2 r;
  r.x = x;
  r.y = x;
  return r;
}
// (k-even, k-odd) bf16 pair -> f32 pair
__device__ __forceinline__ f32x2 unpack_bf2(unsigned u) {
  f32x2 r;
  r.x = __uint_as_float(u << 16);
  r.y = __uint_as_float(u & 0xffff0000u);
  return r;
}
// s += sum_{i=0..3} v_i/(a_i*b_i+1) for BOTH k-parities, ONE rcp per parity.
__device__ __forceinline__ void cell4k(float a0, float a1, float a2, float a3,
                                       f32x2 b0, f32x2 b1, f32x2 b2, f32x2 b3,
                                       float v0, float v1, float v2, float v3,
                                       f32x2& s) {
  const f32x2 one = {1.f, 1.f};
  f32x2 x0 = pkfma(splat2(a0), b0, one);
  f32x2 x1 = pkfma(splat2(a1), b1, one);
  f32x2 x2 = pkfma(splat2(a2), b2, one);
  f32x2 x3 = pkfma(splat2(a3), b3, one);
  f32x2 p01 = x0 * x1, p23 = x2 * x3;
  f32x2 n01 = pkfma(splat2(v0), x1, splat2(v1) * x0);
  f32x2 n23 = pkfma(splat2(v2), x3, splat2(v3) * x2);
  f32x2 num = pkfma(n01, p23, n23 * p01);
  f32x2 den = p01 * p23;
  f32x2 r;
  r.x = frcp(den.x);
  r.y = frcp(den.y);
  s = pkfma(num, r, s);
}

// ---------------------------------------------------------------------------
// K1: Aexp[m][128] = exp(2*query@w1^T) (f32, coalesced),
//     BexpT[h][4096] = exp(2*key@w2^T) transposed (bf16, coalesced via
//     swapped-operand MFMA: mfma(B,A) = (A@B^T)^T so lane&15 -> m).
// M=4096, K=512. BM=32, BN=128, BK=64. grid (128, 2), block 256.
// ---------------------------------------------------------------------------
__global__ __launch_bounds__(256) void k_proj_mfma(
    const float* __restrict__ query, const float* __restrict__ key,
    const float* __restrict__ w1, const float* __restrict__ w2,
    float* __restrict__ Aout, unsigned short* __restrict__ BoutT) {
  const float* in = blockIdx.y ? key : query;
  const float* wm = blockIdx.y ? w2  : w1;

  __shared__ __align__(16) char Abuf[32 * 128];   // [m][k] bf16, swizzled, 4KB
  __shared__ __align__(16) char Bbuf[128 * 128];  // [n][k] bf16, swizzled, 16KB

  const int t = threadIdx.x;
  const int m0g = blockIdx.x * 32;
  const int w = t >> 6, l = t & 63;
  const int wr = w >> 1, wc = w & 1;  // m-half(16) / n-half(64)

  f32x4v acc[4];
  acc[0] = 0; acc[1] = 0; acc[2] = 0; acc[3] = 0;

  const int srow = t >> 3, sg = t & 7;  // staging: row, granule

  for (int k0 = 0; k0 < 512; k0 += 64) {
    if (k0) __syncthreads();
    {  // stage in tile 32m x 64k: 1 granule (8 floats -> 8 bf16) per thread
      const float* src = &in[(m0g + srow) * 512 + k0 + sg * 8];
      float4 f0 = *(const float4*)src;
      float4 f1 = *(const float4*)(src + 4);
      uint4 p = make_uint4(pack2bf(f0.x, f0.y), pack2bf(f0.z, f0.w),
                           pack2bf(f1.x, f1.y), pack2bf(f1.z, f1.w));
      *(uint4*)(Abuf + srow * 128 + ((sg ^ (srow & 7)) << 4)) = p;
    }
#pragma unroll
    for (int i = 0; i < 4; ++i) {  // stage w tile 128n x 64k: 4 granules/thread
      int tt = t + i * 256;
      int row = tt >> 3, g = tt & 7;
      const float* src = &wm[row * 512 + k0 + g * 8];
      float4 f0 = *(const float4*)src;
      float4 f1 = *(const float4*)(src + 4);
      uint4 p = make_uint4(pack2bf(f0.x, f0.y), pack2bf(f0.z, f0.w),
                           pack2bf(f1.x, f1.y), pack2bf(f1.z, f1.w));
      *(uint4*)(Bbuf + row * 128 + ((g ^ (row & 7)) << 4)) = p;
    }
    __syncthreads();
#pragma unroll
    for (int ks = 0; ks < 2; ++ks) {
      const int gb = ks * 4 + (l >> 4);
      int ra = wr * 16 + (l & 15);
      short8 af = *(const short8*)(Abuf + ra * 128 + ((gb ^ (ra & 7)) << 4));
#pragma unroll
      for (int ni = 0; ni < 4; ++ni) {
        int rb = wc * 64 + ni * 16 + (l & 15);
        short8 bf_ = *(const short8*)(Bbuf + rb * 128 + ((gb ^ (rb & 7)) << 4));
        if (blockIdx.y == 0)
          acc[ni] = __builtin_amdgcn_mfma_f32_16x16x32_bf16(af, bf_, acc[ni], 0, 0, 0);
        else  // transposed tile: rows=h, cols=m
          acc[ni] = __builtin_amdgcn_mfma_f32_16x16x32_bf16(bf_, af, acc[ni], 0, 0, 0);
      }
    }
  }
  if (blockIdx.y == 0) {
#pragma unroll
    for (int ni = 0; ni < 4; ++ni) {
      int col = wc * 64 + ni * 16 + (l & 15);  // h
#pragma unroll
      for (int j = 0; j < 4; ++j) {
        int row = m0g + wr * 16 + (l >> 4) * 4 + j;  // m
        Aout[row * 128 + col] = fexp2(acc[ni][j] * TWO_LOG2E);
      }
    }
  } else {
    int m = m0g + wr * 16 + (l & 15);  // contiguous across lanes
#pragma unroll
    for (int ni = 0; ni < 4; ++ni) {
#pragma unroll
      for (int j = 0; j < 4; ++j) {
        int h = wc * 64 + ni * 16 + (l >> 4) * 4 + j;
        BoutT[h * 4096 + m] = f2bf(fexp2(acc[ni][j] * TWO_LOG2E));
      }
    }
  }
}

// ---------------------------------------------------------------------------
// k_valT: valT[b][n][k] = bf16(value[b][k][n]).  64x64 tiles, grid (8,8,8).
// ---------------------------------------------------------------------------
__global__ __launch_bounds__(256) void k_valT(
    const float* __restrict__ value, unsigned short* __restrict__ valT) {
  __shared__ unsigned short ts[64][66];
  const int t = threadIdx.x;
  const int b = blockIdx.z, k0 = blockIdx.y * 64, n0 = blockIdx.x * 64;
  {
    int kr = t >> 4, n4 = (t & 15) * 4;
#pragma unroll
    for (int i = 0; i < 4; ++i) {
      float4 f = *(const float4*)&value[((b * 512) + k0 + kr + 16 * i) * 512 + n0 + n4];
      *(ushort4*)&ts[kr + 16 * i][n4] =
          make_ushort4(f2bf(f.x), f2bf(f.y), f2bf(f.z), f2bf(f.w));
    }
  }
  __syncthreads();
  {
    int nw = t >> 4, k4 = (t & 15) * 4;
#pragma unroll
    for (int i = 0; i < 4; ++i) {
      int n = nw + 16 * i;
      ushort4 o = make_ushort4(ts[k4 + 0][n], ts[k4 + 1][n], ts[k4 + 2][n], ts[k4 + 3][n]);
      *(ushort4*)&valT[((b * 512) + n0 + n) * 512 + k0 + k4] = o;
    }
  }
}

// ---------------------------------------------------------------------------
// K2: S[q,k] = sum_h v[h]/(A[q,h]*B[k,h]+1);  attn = softmax_k(-2S).
// No LDS/barriers in hot loop. B from BexpT[h][k]: lane owns k-pair (2l,2l+1),
// one coalesced dword per h; k-parity lives in the two halves of packed-f32
// (v_pk_fma_f32) math. A,v SGPR-broadcast: s_load_dwordx16 issue early, wait
// late ("+s"-tied asm). 2 q-rows/block, grid (256,8) = 8 blocks/CU.
// ---------------------------------------------------------------------------
__global__ __launch_bounds__(256, 8) void k_score_softmax(
    const float* __restrict__ Aexp, const unsigned short* __restrict__ BexpT,
    const float* __restrict__ vw, float* __restrict__ attn) {
  __shared__ float red[4][2];

  const int tid = threadIdx.x;
  const int b = blockIdx.y;
  const int qbase = blockIdx.x * 2;
  const int wav = tid >> 6;   // k-quarter
  const int lane = tid & 63;

  // B addressing: uniform base (SGPR) + per-lane dword index (hoisted VGPR)
  const unsigned* const bbase32 = (const unsigned*)(BexpT + b * 512);
  const int kidx = wav * 64 + lane;  // dword index within a k-row

  // wave-uniform scalar base pointers for the 2 A rows and v
  const float* const pa0 =
      Aexp + __builtin_amdgcn_readfirstlane((b * 512 + qbase) * 128);
  const float* const pa1 = pa0 + 128;
  const float* const pv = vw;

  f32x2 accq0 = {0.f, 0.f};  // q0: (k-even, k-odd)
  f32x2 accq1 = {0.f, 0.f};  // q1

#pragma unroll
  for (int hc = 0; hc < 8; ++hc) {
    f32x16s sa0, sa1, sv;
    unsigned soff = (unsigned)(hc * 64);
    asm volatile(
        "s_load_dwordx16 %0, %3, %6\n\t"
        "s_load_dwordx16 %1, %4, %6\n\t"
        "s_load_dwordx16 %2, %5, %6"
        : "=&s"(sa0), "=&s"(sa1), "=&s"(sv)
        : "s"(pa0), "s"(pa1), "s"(pv), "s"(soff));

    unsigned u[16];
#pragma unroll
    for (int j = 0; j < 16; ++j)
      u[j] = bbase32[hc * 32768 + j * 2048 + kidx];  // scalar base + v_kidx

    asm volatile("s_waitcnt lgkmcnt(0)" : "+s"(sa0), "+s"(sa1), "+s"(sv));

#pragma unroll
    for (int g = 0; g < 4; ++g) {
      f32x2 b0 = unpack_bf2(u[g * 4 + 0]);
      f32x2 b1 = unpack_bf2(u[g * 4 + 1]);
      f32x2 b2 = unpack_bf2(u[g * 4 + 2]);
      f32x2 b3 = unpack_bf2(u[g * 4 + 3]);
      const int h = g * 4;
      cell4k(sa0[h], sa0[h + 1], sa0[h + 2], sa0[h + 3], b0, b1, b2, b3,
             sv[h], sv[h + 1], sv[h + 2], sv[h + 3], accq0);
      cell4k(sa1[h], sa1[h + 1], sa1[h + 2], sa1[h + 3], b0, b1, b2, b3,
             sv[h], sv[h + 1], sv[h + 2], sv[h + 3], accq1);
    }
  }

  float S00 = accq0.x, S01 = accq0.y, S10 = accq1.x, S11 = accq1.y;

  // softmax over k of (-2S): max(score) <-> min(S). k spans lanes+waves.
  float mn0 = fminf(S00, S01);
  float mn1 = fminf(S10, S11);
#pragma unroll
  for (int off = 32; off > 0; off >>= 1) {
    mn0 = fminf(mn0, __shfl_xor(mn0, off));
    mn1 = fminf(mn1, __shfl_xor(mn1, off));
  }
  if (lane == 0) { red[wav][0] = mn0; red[wav][1] = mn1; }
  __syncthreads();
  mn0 = fminf(fminf(red[0][0], red[1][0]), fminf(red[2][0], red[3][0]));
  mn1 = fminf(fminf(red[0][1], red[1][1]), fminf(red[2][1], red[3][1]));
  __syncthreads();  // before red reuse

  float P00 = fexp2((mn0 - S00) * TWO_LOG2E);
  float P01 = fexp2((mn0 - S01) * TWO_LOG2E);
  float P10 = fexp2((mn1 - S10) * TWO_LOG2E);
  float P11 = fexp2((mn1 - S11) * TWO_LOG2E);
  float sum0 = P00 + P01, sum1 = P10 + P11;
#pragma unroll
  for (int off = 32; off > 0; off >>= 1) {
    sum0 += __shfl_xor(sum0, off);
    sum1 += __shfl_xor(sum1, off);
  }
  if (lane == 0) { red[wav][0] = sum0; red[wav][1] = sum1; }
  __syncthreads();
  float r0 = frcp(red[0][0] + red[1][0] + red[2][0] + red[3][0]);
  float r1 = frcp(red[0][1] + red[1][1] + red[2][1] + red[3][1]);

  const int row0 = (b * 512 + qbase) * 512;
  const int k0 = wav * 128 + lane * 2;
  *(float2*)&attn[row0 + k0] = make_float2(P00 * r0, P01 * r0);
  *(float2*)&attn[row0 + 512 + k0] = make_float2(P10 * r1, P11 * r1);
}

// ---------------------------------------------------------------------------
// K3: context[b] = attn[b] @ value[b] via bf16 MFMA 16x16x32.
// Tile 64x64, BK=64, 4 waves (2x2), wave tile 32x32 (2x2 frags).
// grid (8,8,8), block 256.
// ---------------------------------------------------------------------------
__global__ __launch_bounds__(256) void k_context_mfma(
    const float* __restrict__ attn, const unsigned short* __restrict__ valT,
    float* __restrict__ ctx) {
  __shared__ __align__(16) char At[64 * 128];  // [m][k] bf16 swizzled, 8KB
  __shared__ __align__(16) char Bt[64 * 128];  // [n][k] bf16 swizzled, 8KB

  const int t = threadIdx.x;
  const int b = blockIdx.z;
  const int m0 = blockIdx.y * 64, n0 = blockIdx.x * 64;
  const int w = t >> 6, l = t & 63;
  const int wr = w >> 1, wc = w & 1;

  f32x4v acc[2][2];
  acc[0][0] = 0; acc[0][1] = 0; acc[1][0] = 0; acc[1][1] = 0;

  const int sr = t >> 2;
  const int sg = (t & 3);
  const int sswz = sr & 7;

  for (int k0 = 0; k0 < 512; k0 += 64) {
    if (k0) __syncthreads();
    {  // stage A: 16 f32 -> 16 bf16 per thread
      const float* src = &attn[(b * 512 + m0 + sr) * 512 + k0 + sg * 16];
      char* dst = At + sr * 128;
#pragma unroll
      for (int h = 0; h < 2; ++h) {
        float4 f0 = *(const float4*)(src + h * 8);
        float4 f1 = *(const float4*)(src + h * 8 + 4);
        uint4 p = make_uint4(pack2bf(f0.x, f0.y), pack2bf(f0.z, f0.w),
                             pack2bf(f1.x, f1.y), pack2bf(f1.z, f1.w));
        int g = sg * 2 + h;
        *(uint4*)(dst + ((g ^ sswz) << 4)) = p;
      }
      // stage B^T: 32 bf16 per thread (already bf16)
      const unsigned short* srcb = &valT[(b * 512 + n0 + sr) * 512 + k0];
      char* dstb = Bt + sr * 128;
#pragma unroll
      for (int h = 0; h < 2; ++h) {
        int g = sg + h * 4;
        uint4 vb = *(const uint4*)(srcb + g * 8);
        *(uint4*)(dstb + ((g ^ sswz) << 4)) = vb;
      }
    }
    __syncthreads();
#pragma unroll
    for (int ks = 0; ks < 2; ++ks) {
      const int gb = ks * 4 + (l >> 4);
      short8 af[2], bf_[2];
#pragma unroll
      for (int mi = 0; mi < 2; ++mi) {
        int ra = wr * 32 + mi * 16 + (l & 15);
        af[mi] = *(const short8*)(At + ra * 128 + ((gb ^ (ra & 7)) << 4));
      }
#pragma unroll
      for (int ni = 0; ni < 2; ++ni) {
        int rb = wc * 32 + ni * 16 + (l & 15);
        bf_[ni] = *(const short8*)(Bt + rb * 128 + ((gb ^ (rb & 7)) << 4));
      }
#pragma unroll
      for (int mi = 0; mi < 2; ++mi)
#pragma unroll
        for (int ni = 0; ni < 2; ++ni)
          acc[mi][ni] = __builtin_amdgcn_mfma_f32_16x16x32_bf16(
              af[mi], bf_[ni], acc[mi][ni], 0, 0, 0);
    }
  }
  __syncthreads();
#pragma unroll
  for (int mi = 0; mi < 2; ++mi)
#pragma unroll
    for (int ni = 0; ni < 2; ++ni) {
      int col = n0 + wc * 32 + ni * 16 + (l & 15);
#pragma unroll
      for (int j = 0; j < 4; ++j) {
        int row = m0 + wr * 32 + mi * 16 + (l >> 4) * 4 + j;
        ctx[(b * 512 + row) * 512 + col] = acc[mi][ni][j];
      }
    }
}

extern "C" void kernel_launch(void* const* d_in, const int* in_sizes, int n_in,
                              void* d_out, int out_size, void* d_ws, size_t ws_size,
                              hipStream_t stream) {
  const float* query = (const float*)d_in[0];
  const float* key   = (const float*)d_in[1];
  const float* value = (const float*)d_in[2];
  const float* w1    = (const float*)d_in[3];
  const float* w2    = (const float*)d_in[4];
  const float* v     = (const float*)d_in[5];

  float* attn = (float*)d_out;
  float* ctx  = attn + 8 * 512 * 512;

  float* Aexp = (float*)d_ws;                                    // 4096*128 f32
  unsigned short* BexpT = (unsigned short*)(Aexp + 4096 * 128);  // 128*4096 bf16
  unsigned short* valT = BexpT + 128 * 4096;                     // 8*512*512 bf16

  k_proj_mfma<<<dim3(128, 2), 256, 0, stream>>>(query, key, w1, w2, Aexp, BexpT);
  k_valT<<<dim3(8, 8, 8), 256, 0, stream>>>(value, valT);
  k_score_softmax<<<dim3(256, 8), 256, 0, stream>>>(Aexp, BexpT, v, attn);
  k_context_mfma<<<dim3(8, 8, 8), 256, 0, stream>>>(attn, valT, ctx);
}